// Round 3
// baseline (1131.111 us; speedup 1.0000x reference)
//
#include <hip/hip_runtime.h>

typedef unsigned short u16;
typedef __attribute__((ext_vector_type(8))) short bf16x8;   // 8 bf16 = 4 VGPRs (MFMA A/B frag)
typedef __attribute__((ext_vector_type(4))) float floatx4;  // MFMA C/D frag

__device__ __forceinline__ float bf2f(u16 h) {
  return __uint_as_float(((unsigned int)h) << 16);
}
__device__ __forceinline__ u16 f2bf(float f) {
  unsigned int u = __float_as_uint(f);
  u += 0x7fffu + ((u >> 16) & 1u);  // RNE
  return (u16)(u >> 16);
}
// probe[0] is freqs_cos[0] == 1.0f: fp32 low u16 = 0x0000, bf16 = 0x3F80.
__device__ __forceinline__ bool is_f32(const u16* probe) { return probe[0] == 0; }

// ------------- convert any input buffer (fp32 or bf16 per probe) -> bf16 --------------
__global__ __launch_bounds__(256) void cvt_to_bf16(const void* __restrict__ in,
                                                   u16* __restrict__ out, int n,
                                                   const u16* __restrict__ probe) {
  int i = (blockIdx.x * 256 + threadIdx.x) * 8;
  if (i >= n) return;
  if (is_f32(probe)) {
    const float* f = (const float*)in;
    uint4 o;
    o.x = (unsigned)f2bf(f[i + 0]) | ((unsigned)f2bf(f[i + 1]) << 16);
    o.y = (unsigned)f2bf(f[i + 2]) | ((unsigned)f2bf(f[i + 3]) << 16);
    o.z = (unsigned)f2bf(f[i + 4]) | ((unsigned)f2bf(f[i + 5]) << 16);
    o.w = (unsigned)f2bf(f[i + 6]) | ((unsigned)f2bf(f[i + 7]) << 16);
    *(uint4*)(out + i) = o;
  } else {
    *(uint4*)(out + i) = *(const uint4*)((const u16*)in + i);
  }
}

// ---------- transpose+convert: in (R,C) fp32/bf16 per probe -> out (C,R) bf16 ---------
__global__ __launch_bounds__(256) void transpose_cvt(const void* __restrict__ in,
                                                     u16* __restrict__ out,
                                                     int R, int C,
                                                     const u16* __restrict__ probe) {
  __shared__ u16 tile[32][33];
  int bx = blockIdx.x * 32;  // input col base
  int by = blockIdx.y * 32;  // input row base
  int tx = threadIdx.x & 31, ty = threadIdx.x >> 5;  // 32 x 8
  if (is_f32(probe)) {
    const float* f = (const float*)in;
    for (int i = 0; i < 32; i += 8)
      tile[ty + i][tx] = f2bf(f[(size_t)(by + ty + i) * C + (bx + tx)]);
  } else {
    const u16* u = (const u16*)in;
    for (int i = 0; i < 32; i += 8)
      tile[ty + i][tx] = u[(size_t)(by + ty + i) * C + (bx + tx)];
  }
  __syncthreads();
  for (int i = 0; i < 32; i += 8)
    out[(size_t)(bx + ty + i) * R + (by + tx)] = tile[tx][ty + i];
}

// ---------------- transpose (bf16), batched: in (Z,R,C) -> out (Z,C,R) ----------------
__global__ __launch_bounds__(256) void transpose_bf16(const u16* __restrict__ in,
                                                      u16* __restrict__ out,
                                                      int R, int C) {
  __shared__ u16 tile[32][33];
  size_t base = (size_t)blockIdx.z * R * C;
  int bx = blockIdx.x * 32;
  int by = blockIdx.y * 32;
  int tx = threadIdx.x & 31, ty = threadIdx.x >> 5;
  for (int i = 0; i < 32; i += 8)
    tile[ty + i][tx] = in[base + (size_t)(by + ty + i) * C + (bx + tx)];
  __syncthreads();
  for (int i = 0; i < 32; i += 8)
    out[base + (size_t)(bx + ty + i) * R + (by + tx)] = tile[tx][ty + i];
}

// ---------------- GEMM: C[M,N] = A[M,K] * BT[N,K]^T  (bf16 in, fp32 acc) --------------
// 128x128 tile, 256 threads (4 waves, 2x2), BK=32, mfma 16x16x32 bf16 (m93 structure).
// DYNOUT: epilogue emits fp32 when probe says fp32 world, else bf16.
template <bool DYNOUT>
__global__ __launch_bounds__(256) void gemm_bt(const u16* __restrict__ A,
                                               const u16* __restrict__ BT,
                                               void* __restrict__ Cv,
                                               int M, int N, int K,
                                               const u16* __restrict__ probe) {
  __shared__ __align__(16) u16 As[128 * 32];
  __shared__ __align__(16) u16 Bs[128 * 32];
  const int m0 = blockIdx.y * 128, n0 = blockIdx.x * 128;
  const int t = threadIdx.x;
  const int wave = t >> 6, lane = t & 63;
  const int wm = (wave >> 1) * 64, wn = (wave & 1) * 64;
  const int quad = lane >> 4, l16 = lane & 15;
  floatx4 acc[4][4];
  for (int i = 0; i < 4; ++i)
    for (int j = 0; j < 4; ++j) acc[i][j] = (floatx4){0.f, 0.f, 0.f, 0.f};

  for (int kt = 0; kt < K; kt += 32) {
    __syncthreads();
    for (int i = 0; i < 2; ++i) {
      int e = (i * 256 + t) * 8;  // element idx in [row][k] tile, k inner (32)
      int r = e >> 5, c = e & 31;
      *(uint4*)&As[e] = *(const uint4*)(A + (size_t)(m0 + r) * K + kt + c);
      *(uint4*)&Bs[e] = *(const uint4*)(BT + (size_t)(n0 + r) * K + kt + c);
    }
    __syncthreads();
    bf16x8 af[4], bfr[4];
    for (int i = 0; i < 4; ++i)
      af[i] = *(const bf16x8*)&As[(wm + i * 16 + l16) * 32 + quad * 8];
    for (int j = 0; j < 4; ++j)
      bfr[j] = *(const bf16x8*)&Bs[(wn + j * 16 + l16) * 32 + quad * 8];
    for (int i = 0; i < 4; ++i)
      for (int j = 0; j < 4; ++j)
        acc[i][j] = __builtin_amdgcn_mfma_f32_16x16x32_bf16(af[i], bfr[j], acc[i][j], 0, 0, 0);
  }
  // epilogue: C row = quad*4+reg, col = l16 (verified m89/m91 layout)
  const bool f32out = DYNOUT && is_f32(probe);
  for (int i = 0; i < 4; ++i) {
    int rbase = m0 + wm + i * 16 + quad * 4;
    for (int j = 0; j < 4; ++j) {
      int col = n0 + wn + j * 16 + l16;
      for (int r = 0; r < 4; ++r) {
        if (f32out)
          ((float*)Cv)[(size_t)(rbase + r) * N + col] = acc[i][j][r];
        else
          ((u16*)Cv)[(size_t)(rbase + r) * N + col] = f2bf(acc[i][j][r]);
      }
    }
  }
}

// ---------------- RMSNorm over rows of 512, in place (bf16) ---------------------------
__global__ __launch_bounds__(256) void rmsnorm_kernel(u16* __restrict__ t,
                                                      const u16* __restrict__ w) {
  int row = blockIdx.x * 4 + (threadIdx.x >> 6);
  int lane = threadIdx.x & 63;
  u16* xr = t + (size_t)row * 512;
  float v[8];
  float ss = 0.f;
  for (int i = 0; i < 8; ++i) {
    v[i] = bf2f(xr[lane + i * 64]);
    ss += v[i] * v[i];
  }
  for (int d = 32; d > 0; d >>= 1) ss += __shfl_xor(ss, d);
  float r = rsqrtf(ss * (1.f / 512.f) + 1e-6f);
  for (int i = 0; i < 8; ++i) xr[lane + i * 64] = f2bf(v[i] * r * bf2f(w[lane + i * 64]));
}

// ---------------- RoPE, interleaved pairs, in-place. t: (B,S,16,128) bf16 -------------
__global__ __launch_bounds__(256) void rope_kernel(u16* __restrict__ t,
                                                   const u16* __restrict__ fc,
                                                   const u16* __restrict__ fs) {
  unsigned int idx = blockIdx.x * 256 + threadIdx.x;  // pair idx: p[5:0] h[9:6] s[20:10] b[21]
  int p = idx & 63;
  int s = (idx >> 10) & 2047;
  unsigned int pk = *(const unsigned int*)(t + (size_t)idx * 2);
  float x1 = bf2f((u16)(pk & 0xffffu));
  float x2 = bf2f((u16)(pk >> 16));
  float c = bf2f(fc[s * 64 + p]);
  float sv = bf2f(fs[s * 64 + p]);
  float o1 = x1 * c - x2 * sv;
  float o2 = x1 * sv + x2 * c;
  unsigned int ou = (unsigned int)f2bf(o1) | ((unsigned int)f2bf(o2) << 16);
  *(unsigned int*)(t + (size_t)idx * 2) = ou;
}

// ---------------- Flash attention (causal), bf16 MFMA, fp32 softmax -------------------
// q,k: (B,S,H*128) post-RoPE.  vt: (B,H,128,S).  o: (B,S,H*128).
__global__ __launch_bounds__(256) void attn_kernel(const u16* __restrict__ q,
                                                   const u16* __restrict__ k,
                                                   const u16* __restrict__ vt,
                                                   u16* __restrict__ o, int S) {
  __shared__ __align__(16) u16 P[4][16][64];
  const int w = threadIdx.x >> 6, lane = threadIdx.x & 63;
  const int quad = lane >> 4, l16 = lane & 15;
  const int bh = blockIdx.y;
  const int b = bh >> 4, h = bh & 15;
  const int q0 = blockIdx.x * 64 + w * 16;
  const float scale = 0.08838834764831845f;  // 1/sqrt(128)

  const u16* qbase = q + ((size_t)(b * S + q0 + l16)) * 2048 + h * 128;
  bf16x8 qf[4];
  for (int c = 0; c < 4; ++c) qf[c] = *(const bf16x8*)(qbase + c * 32 + quad * 8);

  float m_i[4], l_i[4];
  floatx4 acc[8];
  for (int r = 0; r < 4; ++r) { m_i[r] = -1e30f; l_i[r] = 0.f; }
  for (int nd = 0; nd < 8; ++nd) acc[nd] = (floatx4){0.f, 0.f, 0.f, 0.f};

  const int kmax = q0 + 15;
  const u16* vtb = vt + (size_t)bh * 128 * S;

  for (int kb = 0; kb <= kmax; kb += 64) {
    floatx4 s[4];
    for (int ns = 0; ns < 4; ++ns) {
      s[ns] = (floatx4){0.f, 0.f, 0.f, 0.f};
      const u16* kp = k + ((size_t)(b * S + kb + ns * 16 + l16)) * 2048 + h * 128;
      for (int c = 0; c < 4; ++c) {
        bf16x8 kf = *(const bf16x8*)(kp + c * 32 + quad * 8);
        s[ns] = __builtin_amdgcn_mfma_f32_16x16x32_bf16(qf[c], kf, s[ns], 0, 0, 0);
      }
    }
    for (int ns = 0; ns < 4; ++ns) {
      int key = kb + ns * 16 + l16;
      for (int r = 0; r < 4; ++r) {
        float sv = s[ns][r] * scale;
        s[ns][r] = (key > q0 + quad * 4 + r) ? -1e30f : sv;
      }
    }
    float alpha[4];
    for (int r = 0; r < 4; ++r) {
      float v = fmaxf(fmaxf(s[0][r], s[1][r]), fmaxf(s[2][r], s[3][r]));
      for (int d = 1; d < 16; d <<= 1) v = fmaxf(v, __shfl_xor(v, d));
      float mn = fmaxf(m_i[r], v);
      alpha[r] = __expf(m_i[r] - mn);
      m_i[r] = mn;
    }
    for (int ns = 0; ns < 4; ++ns)
      for (int r = 0; r < 4; ++r) s[ns][r] = __expf(s[ns][r] - m_i[r]);
    for (int r = 0; r < 4; ++r) {
      float v = s[0][r] + s[1][r] + s[2][r] + s[3][r];
      for (int d = 1; d < 16; d <<= 1) v += __shfl_xor(v, d);
      l_i[r] = l_i[r] * alpha[r] + v;
    }
    for (int nd = 0; nd < 8; ++nd)
      for (int r = 0; r < 4; ++r) acc[nd][r] *= alpha[r];
    for (int ns = 0; ns < 4; ++ns)
      for (int r = 0; r < 4; ++r) P[w][quad * 4 + r][ns * 16 + l16] = f2bf(s[ns][r]);
    for (int kc = 0; kc < 2; ++kc) {
      bf16x8 pa = *(const bf16x8*)&P[w][l16][kc * 32 + quad * 8];
      for (int nd = 0; nd < 8; ++nd) {
        bf16x8 vf = *(const bf16x8*)(vtb + (size_t)(nd * 16 + l16) * S + kb + kc * 32 + quad * 8);
        acc[nd] = __builtin_amdgcn_mfma_f32_16x16x32_bf16(pa, vf, acc[nd], 0, 0, 0);
      }
    }
  }
  u16* ob = o + ((size_t)(b * S + q0 + quad * 4)) * 2048 + h * 128;
  for (int r = 0; r < 4; ++r) {
    float inv = 1.f / l_i[r];
    for (int nd = 0; nd < 8; ++nd)
      ob[(size_t)r * 2048 + nd * 16 + l16] = f2bf(acc[nd][r] * inv);
  }
}

// ------------------------------------ launcher ---------------------------------------
// Workspace: 83 MiB, lifetime-aliased. Input dtype (fp32 vs bf16) detected on-device
// from freqs_cos[0] (fp32 1.0f low u16 == 0x0000; bf16 1.0 == 0x3F80).
extern "C" void kernel_launch(void* const* d_in, const int* in_sizes, int n_in,
                              void* d_out, int out_size, void* d_ws, size_t ws_size,
                              hipStream_t stream) {
  const void* x    = d_in[0];  // (2,2048,2048)
  const void* fcos = d_in[1];  // (2048,64)
  const void* fsin = d_in[2];
  const void* wkv  = d_in[3];  // (2048,512)
  const void* wnr  = d_in[4];  // (512,)
  const void* wku  = d_in[5];  // (512,2048)
  const void* wvu  = d_in[6];  // (512,2048)
  const void* wq   = d_in[7];  // (2048,2048)
  const void* wo   = d_in[8];  // (2048,2048)
  const u16* probe = (const u16*)fcos;

  const size_t MB = 1u << 20;
  char* ws = (char*)d_ws;
  u16* xc    = (u16*)(ws);             // 16 MiB x in bf16; dead after gemmQ+gemmKV
  u16* vtb   = (u16*)(ws);             //   ... then V^T (B,H,128,S)
  u16* qb    = (u16*)(ws + 16 * MB);   // 16 MiB
  u16* kb    = (u16*)(ws + 32 * MB);   // 16 MiB
  u16* vb    = (u16*)(ws + 48 * MB);   // 16 MiB V; dead after transposeV
  u16* ab    = (u16*)(ws + 48 * MB);   //   ... then attention output
  u16* lat   = (u16*)(ws + 64 * MB);   // 4 MiB
  u16* wqT   = (u16*)(ws + 68 * MB);   // 8 MiB; dead after gemmQ
  u16* woT   = (u16*)(ws + 68 * MB);   //   ... then w_out^T
  u16* wkvT  = (u16*)(ws + 76 * MB);   // 2 MiB
  u16* wkT   = (u16*)(ws + 78 * MB);   // 2 MiB
  u16* wvT   = (u16*)(ws + 80 * MB);   // 2 MiB
  u16* fcosc = (u16*)(ws + 82 * MB);   // 256 KiB
  u16* fsinc = (u16*)(ws + 82 * MB + 256 * 1024);
  u16* wnrc  = (u16*)(ws + 82 * MB + 512 * 1024);  // 1 KiB  (total < 83 MiB)

  dim3 blk(256);
  // --- convert inputs to bf16 (identity copy if already bf16) ---
  cvt_to_bf16<<<dim3(4096), blk, 0, stream>>>(x, xc, 8388608, probe);
  cvt_to_bf16<<<dim3(64), blk, 0, stream>>>(fcos, fcosc, 131072, probe);
  cvt_to_bf16<<<dim3(64), blk, 0, stream>>>(fsin, fsinc, 131072, probe);
  cvt_to_bf16<<<dim3(1), blk, 0, stream>>>(wnr, wnrc, 512, probe);

  // --- Q path ---
  transpose_cvt<<<dim3(64, 64), blk, 0, stream>>>(wq, wqT, 2048, 2048, probe);
  gemm_bt<false><<<dim3(16, 32), blk, 0, stream>>>(xc, wqT, qb, 4096, 2048, 2048, probe);
  rope_kernel<<<dim3(16384), blk, 0, stream>>>(qb, fcosc, fsinc);

  // --- KV latent ---
  transpose_cvt<<<dim3(16, 64), blk, 0, stream>>>(wkv, wkvT, 2048, 512, probe);
  gemm_bt<false><<<dim3(4, 32), blk, 0, stream>>>(xc, wkvT, lat, 4096, 512, 2048, probe);
  rmsnorm_kernel<<<dim3(1024), blk, 0, stream>>>(lat, wnrc);

  // --- K, V up-projections ---
  transpose_cvt<<<dim3(64, 16), blk, 0, stream>>>(wku, wkT, 512, 2048, probe);
  gemm_bt<false><<<dim3(16, 32), blk, 0, stream>>>(lat, wkT, kb, 4096, 2048, 512, probe);
  rope_kernel<<<dim3(16384), blk, 0, stream>>>(kb, fcosc, fsinc);
  transpose_cvt<<<dim3(64, 16), blk, 0, stream>>>(wvu, wvT, 512, 2048, probe);
  gemm_bt<false><<<dim3(16, 32), blk, 0, stream>>>(lat, wvT, vb, 4096, 2048, 512, probe);

  // --- V -> (B,H,128,S); xc dead by now. w_out^T into dead wqT slot ---
  transpose_bf16<<<dim3(64, 64, 2), blk, 0, stream>>>(vb, vtb, 2048, 2048);
  transpose_cvt<<<dim3(64, 64), blk, 0, stream>>>(wo, woT, 2048, 2048, probe);

  // --- causal flash attention (ab aliases dead vb) ---
  attn_kernel<<<dim3(32, 32), blk, 0, stream>>>(qb, kb, vtb, ab, 2048);

  // --- output projection; epilogue dtype follows probe ---
  gemm_bt<true><<<dim3(16, 32), blk, 0, stream>>>(ab, woT, (u16*)d_out, 4096, 2048, 2048, probe);
}

// Round 4
// 799.565 us; speedup vs baseline: 1.4147x; 1.4147x over previous
//
#include <hip/hip_runtime.h>

typedef unsigned short u16;
typedef __attribute__((ext_vector_type(8))) short bf16x8;   // 8 bf16 = 4 VGPRs (MFMA A/B frag)
typedef __attribute__((ext_vector_type(4))) float floatx4;  // MFMA C/D frag

__device__ __forceinline__ float bf2f(u16 h) {
  return __uint_as_float(((unsigned int)h) << 16);
}
__device__ __forceinline__ u16 f2bf(float f) {
  unsigned int u = __float_as_uint(f);
  u += 0x7fffu + ((u >> 16) & 1u);  // RNE
  return (u16)(u >> 16);
}
// probe[0] is freqs_cos[0] == 1.0f: fp32 low u16 = 0x0000, bf16 = 0x3F80.
__device__ __forceinline__ bool is_f32(const u16* probe) { return probe[0] == 0; }

// async global->LDS, 16B per lane. LDS dest must be wave-uniform base + lane*16.
#define GLOAD_LDS16(gsrc, ldst)                                                        \
  __builtin_amdgcn_global_load_lds(                                                    \
      (const __attribute__((address_space(1))) unsigned int*)(gsrc),                   \
      (__attribute__((address_space(3))) unsigned int*)(ldst), 16, 0, 0)

// ------------- convert any input buffer (fp32 or bf16 per probe) -> bf16 --------------
__global__ __launch_bounds__(256) void cvt_to_bf16(const void* __restrict__ in,
                                                   u16* __restrict__ out, int n,
                                                   const u16* __restrict__ probe) {
  int i = (blockIdx.x * 256 + threadIdx.x) * 8;
  if (i >= n) return;
  if (is_f32(probe)) {
    const float* f = (const float*)in;
    uint4 o;
    o.x = (unsigned)f2bf(f[i + 0]) | ((unsigned)f2bf(f[i + 1]) << 16);
    o.y = (unsigned)f2bf(f[i + 2]) | ((unsigned)f2bf(f[i + 3]) << 16);
    o.z = (unsigned)f2bf(f[i + 4]) | ((unsigned)f2bf(f[i + 5]) << 16);
    o.w = (unsigned)f2bf(f[i + 6]) | ((unsigned)f2bf(f[i + 7]) << 16);
    *(uint4*)(out + i) = o;
  } else {
    *(uint4*)(out + i) = *(const uint4*)((const u16*)in + i);
  }
}

// ---------- transpose+convert: in (R,C) fp32/bf16 per probe -> out (C,R) bf16 ---------
__global__ __launch_bounds__(256) void transpose_cvt(const void* __restrict__ in,
                                                     u16* __restrict__ out,
                                                     int R, int C,
                                                     const u16* __restrict__ probe) {
  __shared__ u16 tile[32][33];
  int bx = blockIdx.x * 32;  // input col base
  int by = blockIdx.y * 32;  // input row base
  int tx = threadIdx.x & 31, ty = threadIdx.x >> 5;  // 32 x 8
  if (is_f32(probe)) {
    const float* f = (const float*)in;
    for (int i = 0; i < 32; i += 8)
      tile[ty + i][tx] = f2bf(f[(size_t)(by + ty + i) * C + (bx + tx)]);
  } else {
    const u16* u = (const u16*)in;
    for (int i = 0; i < 32; i += 8)
      tile[ty + i][tx] = u[(size_t)(by + ty + i) * C + (bx + tx)];
  }
  __syncthreads();
  for (int i = 0; i < 32; i += 8)
    out[(size_t)(bx + ty + i) * R + (by + tx)] = tile[tx][ty + i];
}

// ---------------- transpose (bf16), batched: in (Z,R,C) -> out (Z,C,R) ----------------
__global__ __launch_bounds__(256) void transpose_bf16(const u16* __restrict__ in,
                                                      u16* __restrict__ out,
                                                      int R, int C) {
  __shared__ u16 tile[32][33];
  size_t base = (size_t)blockIdx.z * R * C;
  int bx = blockIdx.x * 32;
  int by = blockIdx.y * 32;
  int tx = threadIdx.x & 31, ty = threadIdx.x >> 5;
  for (int i = 0; i < 32; i += 8)
    tile[ty + i][tx] = in[base + (size_t)(by + ty + i) * C + (bx + tx)];
  __syncthreads();
  for (int i = 0; i < 32; i += 8)
    out[base + (size_t)(bx + ty + i) * R + (by + tx)] = tile[tx][ty + i];
}

// ---------------- GEMM: C[M,N] = A[M,K] * BT[N,K]^T  (bf16 in, fp32 acc) --------------
// 128x128 tile, 256 threads (4 waves, 2x2), BK=32, mfma 16x16x32 bf16,
// global_load_lds width-16 staging (m97 structure).
template <bool DYNOUT>
__global__ __launch_bounds__(256) void gemm_bt(const u16* __restrict__ A,
                                               const u16* __restrict__ BT,
                                               void* __restrict__ Cv,
                                               int M, int N, int K,
                                               const u16* __restrict__ probe) {
  __shared__ __align__(16) u16 As[128 * 32];
  __shared__ __align__(16) u16 Bs[128 * 32];
  const int m0 = blockIdx.y * 128, n0 = blockIdx.x * 128;
  const int t = threadIdx.x;
  const int wave = t >> 6, lane = t & 63;
  const int wm = (wave >> 1) * 64, wn = (wave & 1) * 64;
  const int quad = lane >> 4, l16 = lane & 15;
  floatx4 acc[4][4];
  for (int i = 0; i < 4; ++i)
    for (int j = 0; j < 4; ++j) acc[i][j] = (floatx4){0.f, 0.f, 0.f, 0.f};

  for (int kt = 0; kt < K; kt += 32) {
    __syncthreads();
    for (int i = 0; i < 2; ++i) {
      int e = (i * 256 + t) * 8;  // element idx in [row][k] tile, k inner (32); lane-contiguous 16B
      int r = e >> 5, c = e & 31;
      GLOAD_LDS16(A + (size_t)(m0 + r) * K + kt + c, As + e);
      GLOAD_LDS16(BT + (size_t)(n0 + r) * K + kt + c, Bs + e);
    }
    __syncthreads();
    bf16x8 af[4], bfr[4];
    for (int i = 0; i < 4; ++i)
      af[i] = *(const bf16x8*)&As[(wm + i * 16 + l16) * 32 + quad * 8];
    for (int j = 0; j < 4; ++j)
      bfr[j] = *(const bf16x8*)&Bs[(wn + j * 16 + l16) * 32 + quad * 8];
    for (int i = 0; i < 4; ++i)
      for (int j = 0; j < 4; ++j)
        acc[i][j] = __builtin_amdgcn_mfma_f32_16x16x32_bf16(af[i], bfr[j], acc[i][j], 0, 0, 0);
  }
  // epilogue: C row = quad*4+reg, col = l16 (verified m89/m91 layout)
  const bool f32out = DYNOUT && is_f32(probe);
  for (int i = 0; i < 4; ++i) {
    int rbase = m0 + wm + i * 16 + quad * 4;
    for (int j = 0; j < 4; ++j) {
      int col = n0 + wn + j * 16 + l16;
      for (int r = 0; r < 4; ++r) {
        if (f32out)
          ((float*)Cv)[(size_t)(rbase + r) * N + col] = acc[i][j][r];
        else
          ((u16*)Cv)[(size_t)(rbase + r) * N + col] = f2bf(acc[i][j][r]);
      }
    }
  }
}

// ---------------- RMSNorm over rows of 512, in place (bf16) ---------------------------
__global__ __launch_bounds__(256) void rmsnorm_kernel(u16* __restrict__ t,
                                                      const u16* __restrict__ w) {
  int row = blockIdx.x * 4 + (threadIdx.x >> 6);
  int lane = threadIdx.x & 63;
  u16* xr = t + (size_t)row * 512;
  float v[8];
  float ss = 0.f;
  for (int i = 0; i < 8; ++i) {
    v[i] = bf2f(xr[lane + i * 64]);
    ss += v[i] * v[i];
  }
  for (int d = 32; d > 0; d >>= 1) ss += __shfl_xor(ss, d);
  float r = rsqrtf(ss * (1.f / 512.f) + 1e-6f);
  for (int i = 0; i < 8; ++i) xr[lane + i * 64] = f2bf(v[i] * r * bf2f(w[lane + i * 64]));
}

// ---------------- RoPE, interleaved pairs, in-place. t: (B,S,16,128) bf16 -------------
__global__ __launch_bounds__(256) void rope_kernel(u16* __restrict__ t,
                                                   const u16* __restrict__ fc,
                                                   const u16* __restrict__ fs) {
  unsigned int idx = blockIdx.x * 256 + threadIdx.x;  // pair idx: p[5:0] h[9:6] s[20:10] b[21]
  int p = idx & 63;
  int s = (idx >> 10) & 2047;
  unsigned int pk = *(const unsigned int*)(t + (size_t)idx * 2);
  float x1 = bf2f((u16)(pk & 0xffffu));
  float x2 = bf2f((u16)(pk >> 16));
  float c = bf2f(fc[s * 64 + p]);
  float sv = bf2f(fs[s * 64 + p]);
  float o1 = x1 * c - x2 * sv;
  float o2 = x1 * sv + x2 * c;
  unsigned int ou = (unsigned int)f2bf(o1) | ((unsigned int)f2bf(o2) << 16);
  *(unsigned int*)(t + (size_t)idx * 2) = ou;
}

// ---------------- Flash attention (causal), bf16 MFMA, fp32 softmax -------------------
// q,k: (B,S,H*128) post-RoPE.  vt: (B,H,128,S).  o: (B,S,H*128).
// Block = 4 waves sharing one (qb,bh): wave w owns q rows q0=qb*64+w*16.
// K-tile (64x128) staged in LDS via global_load_lds, XOR-swizzled chunks
// (chunk^row&15) so frag ds_read_b128 is 2-way max. qb reversed: heavy blocks first.
__global__ __launch_bounds__(256) void attn_kernel(const u16* __restrict__ q,
                                                   const u16* __restrict__ k,
                                                   const u16* __restrict__ vt,
                                                   u16* __restrict__ o) {
  const int S = 2048;
  __shared__ __align__(16) u16 Kt[64 * 128];   // [key][chunk ^ (key&15)], chunks of 8
  __shared__ __align__(16) u16 P[4][16][72];   // +8 pad: pa reads 2-way max
  const int t = threadIdx.x;
  const int w = t >> 6, lane = t & 63;
  const int quad = lane >> 4, l16 = lane & 15;
  const int bh = blockIdx.x;
  const int b = bh >> 4, h = bh & 15;
  const int qb = (int)gridDim.y - 1 - (int)blockIdx.y;  // heaviest first
  const int q0 = qb * 64 + w * 16;
  const float scale = 0.08838834764831845f;  // 1/sqrt(128)

  // Q fragments (A layout: m=l16, k=quad*8+j), 4 dim-chunks of 32
  const u16* qbase = q + ((size_t)(b * S + q0 + l16)) * 2048 + h * 128;
  bf16x8 qf[4];
  for (int c = 0; c < 4; ++c) qf[c] = *(const bf16x8*)(qbase + c * 32 + quad * 8);

  const u16* kbase = k + (size_t)b * S * 2048 + h * 128;
  const u16* vtb = vt + (size_t)bh * 128 * S;

  // staging decode for this thread: per issue j covers rows j*16 + (t>>4)
  const int srow = t >> 4;  // 0..15
  const int sv = t & 15;    // LDS slot chunk

  float m_i[4], l_i[4];
  floatx4 acc[8];
  for (int r = 0; r < 4; ++r) { m_i[r] = -1e30f; l_i[r] = 0.f; }
  for (int nd = 0; nd < 8; ++nd) acc[nd] = (floatx4){0.f, 0.f, 0.f, 0.f};

  const int kmax = q0 + 15;  // last unmasked key for this wave
  for (int kb = 0; kb <= qb * 64; kb += 64) {
    __syncthreads();  // all waves done reading Kt from previous step
    for (int j = 0; j < 4; ++j) {
      int row = j * 16 + srow;
      int chunk = sv ^ (row & 15);
      GLOAD_LDS16(kbase + (size_t)(kb + row) * 2048 + chunk * 8,
                  Kt + ((size_t)(row * 16 + sv)) * 8);
    }
    __syncthreads();  // staging drained (compiler: s_waitcnt vmcnt(0) before s_barrier)

    // ---- scores (skip fully-masked 16-key sub-blocks on the diagonal step) ----
    floatx4 s[4];
    for (int ns = 0; ns < 4; ++ns) {
      if (kb + ns * 16 <= kmax) {
        s[ns] = (floatx4){0.f, 0.f, 0.f, 0.f};
        for (int c = 0; c < 4; ++c) {
          bf16x8 kf = *(const bf16x8*)&Kt[(ns * 16 + l16) * 128 + ((c * 4 + quad) ^ l16) * 8];
          s[ns] = __builtin_amdgcn_mfma_f32_16x16x32_bf16(qf[c], kf, s[ns], 0, 0, 0);
        }
        int key = kb + ns * 16 + l16;
        for (int r = 0; r < 4; ++r) {
          float x = s[ns][r] * scale;
          s[ns][r] = (key > q0 + quad * 4 + r) ? -1e30f : x;
        }
      } else {
        s[ns] = (floatx4){-1e30f, -1e30f, -1e30f, -1e30f};
      }
    }
    // ---- online softmax (16-lane butterfly; score row = quad*4+r, col = l16) ----
    float alpha[4];
    for (int r = 0; r < 4; ++r) {
      float v = fmaxf(fmaxf(s[0][r], s[1][r]), fmaxf(s[2][r], s[3][r]));
      for (int d = 1; d < 16; d <<= 1) v = fmaxf(v, __shfl_xor(v, d));
      float mn = fmaxf(m_i[r], v);
      alpha[r] = __expf(m_i[r] - mn);
      m_i[r] = mn;
    }
    for (int ns = 0; ns < 4; ++ns)
      for (int r = 0; r < 4; ++r) s[ns][r] = __expf(s[ns][r] - m_i[r]);
    for (int r = 0; r < 4; ++r) {
      float v = s[0][r] + s[1][r] + s[2][r] + s[3][r];
      for (int d = 1; d < 16; d <<= 1) v += __shfl_xor(v, d);
      l_i[r] = l_i[r] * alpha[r] + v;
    }
    for (int nd = 0; nd < 8; ++nd)
      for (int r = 0; r < 4; ++r) acc[nd][r] *= alpha[r];
    // ---- P to LDS (C layout -> A layout) ----
    for (int ns = 0; ns < 4; ++ns)
      for (int r = 0; r < 4; ++r) P[w][quad * 4 + r][ns * 16 + l16] = f2bf(s[ns][r]);
    // ---- PV: O += P(16x64) * V(64x128), V^T frags from global ----
    for (int kc = 0; kc < 2; ++kc) {
      if (kb + kc * 32 <= kmax) {
        bf16x8 pa = *(const bf16x8*)&P[w][l16][kc * 32 + quad * 8];
        for (int nd = 0; nd < 8; ++nd) {
          bf16x8 vf = *(const bf16x8*)(vtb + (size_t)(nd * 16 + l16) * S + kb + kc * 32 + quad * 8);
          acc[nd] = __builtin_amdgcn_mfma_f32_16x16x32_bf16(pa, vf, acc[nd], 0, 0, 0);
        }
      }
    }
  }
  // ---- epilogue ----
  u16* ob = o + ((size_t)(b * S + q0 + quad * 4)) * 2048 + h * 128;
  for (int r = 0; r < 4; ++r) {
    float inv = 1.f / l_i[r];
    for (int nd = 0; nd < 8; ++nd)
      ob[(size_t)r * 2048 + nd * 16 + l16] = f2bf(acc[nd][r] * inv);
  }
}

// ------------------------------------ launcher ---------------------------------------
// Workspace: 83 MiB, lifetime-aliased. Input dtype (fp32 vs bf16) detected on-device
// from freqs_cos[0] (fp32 1.0f low u16 == 0x0000; bf16 1.0 == 0x3F80).
extern "C" void kernel_launch(void* const* d_in, const int* in_sizes, int n_in,
                              void* d_out, int out_size, void* d_ws, size_t ws_size,
                              hipStream_t stream) {
  const void* x    = d_in[0];  // (2,2048,2048)
  const void* fcos = d_in[1];  // (2048,64)
  const void* fsin = d_in[2];
  const void* wkv  = d_in[3];  // (2048,512)
  const void* wnr  = d_in[4];  // (512,)
  const void* wku  = d_in[5];  // (512,2048)
  const void* wvu  = d_in[6];  // (512,2048)
  const void* wq   = d_in[7];  // (2048,2048)
  const void* wo   = d_in[8];  // (2048,2048)
  const u16* probe = (const u16*)fcos;

  const size_t MB = 1u << 20;
  char* ws = (char*)d_ws;
  u16* xc    = (u16*)(ws);             // 16 MiB x in bf16; dead after gemmQ+gemmKV
  u16* vtb   = (u16*)(ws);             //   ... then V^T (B,H,128,S)
  u16* qb    = (u16*)(ws + 16 * MB);   // 16 MiB
  u16* kb    = (u16*)(ws + 32 * MB);   // 16 MiB
  u16* vb    = (u16*)(ws + 48 * MB);   // 16 MiB V; dead after transposeV
  u16* ab    = (u16*)(ws + 48 * MB);   //   ... then attention output
  u16* lat   = (u16*)(ws + 64 * MB);   // 4 MiB
  u16* wqT   = (u16*)(ws + 68 * MB);   // 8 MiB; dead after gemmQ
  u16* woT   = (u16*)(ws + 68 * MB);   //   ... then w_out^T
  u16* wkvT  = (u16*)(ws + 76 * MB);   // 2 MiB
  u16* wkT   = (u16*)(ws + 78 * MB);   // 2 MiB
  u16* wvT   = (u16*)(ws + 80 * MB);   // 2 MiB
  u16* fcosc = (u16*)(ws + 82 * MB);   // 256 KiB
  u16* fsinc = (u16*)(ws + 82 * MB + 256 * 1024);
  u16* wnrc  = (u16*)(ws + 82 * MB + 512 * 1024);  // 1 KiB  (total < 83 MiB)

  dim3 blk(256);
  // --- convert inputs to bf16 (identity copy if already bf16) ---
  cvt_to_bf16<<<dim3(4096), blk, 0, stream>>>(x, xc, 8388608, probe);
  cvt_to_bf16<<<dim3(64), blk, 0, stream>>>(fcos, fcosc, 131072, probe);
  cvt_to_bf16<<<dim3(64), blk, 0, stream>>>(fsin, fsinc, 131072, probe);
  cvt_to_bf16<<<dim3(1), blk, 0, stream>>>(wnr, wnrc, 512, probe);

  // --- Q path ---
  transpose_cvt<<<dim3(64, 64), blk, 0, stream>>>(wq, wqT, 2048, 2048, probe);
  gemm_bt<false><<<dim3(16, 32), blk, 0, stream>>>(xc, wqT, qb, 4096, 2048, 2048, probe);
  rope_kernel<<<dim3(16384), blk, 0, stream>>>(qb, fcosc, fsinc);

  // --- KV latent ---
  transpose_cvt<<<dim3(16, 64), blk, 0, stream>>>(wkv, wkvT, 2048, 512, probe);
  gemm_bt<false><<<dim3(4, 32), blk, 0, stream>>>(xc, wkvT, lat, 4096, 512, 2048, probe);
  rmsnorm_kernel<<<dim3(1024), blk, 0, stream>>>(lat, wnrc);

  // --- K, V up-projections ---
  transpose_cvt<<<dim3(64, 16), blk, 0, stream>>>(wku, wkT, 512, 2048, probe);
  gemm_bt<false><<<dim3(16, 32), blk, 0, stream>>>(lat, wkT, kb, 4096, 2048, 512, probe);
  rope_kernel<<<dim3(16384), blk, 0, stream>>>(kb, fcosc, fsinc);
  transpose_cvt<<<dim3(64, 16), blk, 0, stream>>>(wvu, wvT, 512, 2048, probe);
  gemm_bt<false><<<dim3(16, 32), blk, 0, stream>>>(lat, wvT, vb, 4096, 2048, 512, probe);

  // --- V -> (B,H,128,S); xc dead by now. w_out^T into dead wqT slot ---
  transpose_bf16<<<dim3(64, 64, 2), blk, 0, stream>>>(vb, vtb, 2048, 2048);
  transpose_cvt<<<dim3(64, 64), blk, 0, stream>>>(wo, woT, 2048, 2048, probe);

  // --- causal flash attention (ab aliases dead vb; x=bh, y=qb reversed) ---
  attn_kernel<<<dim3(32, 32), blk, 0, stream>>>(qb, kb, vtb, ab);

  // --- output projection; epilogue dtype follows probe ---
  gemm_bt<true><<<dim3(16, 32), blk, 0, stream>>>(ab, woT, (u16*)d_out, 4096, 2048, 2048, probe);
}

// Round 5
// 464.620 us; speedup vs baseline: 2.4345x; 1.7209x over previous
//
#include <hip/hip_runtime.h>

typedef unsigned short u16;
typedef __attribute__((ext_vector_type(8))) short bf16x8;   // 8 bf16 = 4 VGPRs (MFMA A/B frag)
typedef __attribute__((ext_vector_type(4))) float floatx4;  // MFMA C/D frag

__device__ __forceinline__ float bf2f(u16 h) {
  return __uint_as_float(((unsigned int)h) << 16);
}
__device__ __forceinline__ u16 f2bf(float f) {
  unsigned int u = __float_as_uint(f);
  u += 0x7fffu + ((u >> 16) & 1u);  // RNE
  return (u16)(u >> 16);
}
// probe[0] is freqs_cos[0] == 1.0f: fp32 low u16 = 0x0000, bf16 = 0x3F80.
__device__ __forceinline__ bool is_f32(const u16* probe) { return probe[0] == 0; }

// async global->LDS, 16B per lane. LDS dest must be wave-uniform base + lane*16.
#define GLOAD_LDS16(gsrc, ldst)                                                        \
  __builtin_amdgcn_global_load_lds(                                                    \
      (const __attribute__((address_space(1))) unsigned int*)(gsrc),                   \
      (__attribute__((address_space(3))) unsigned int*)(ldst), 16, 0, 0)

// ------------- convert any input buffer (fp32 or bf16 per probe) -> bf16 --------------
__global__ __launch_bounds__(256) void cvt_to_bf16(const void* __restrict__ in,
                                                   u16* __restrict__ out, int n,
                                                   const u16* __restrict__ probe) {
  int i = (blockIdx.x * 256 + threadIdx.x) * 8;
  if (i >= n) return;
  if (is_f32(probe)) {
    const float* f = (const float*)in;
    uint4 o;
    o.x = (unsigned)f2bf(f[i + 0]) | ((unsigned)f2bf(f[i + 1]) << 16);
    o.y = (unsigned)f2bf(f[i + 2]) | ((unsigned)f2bf(f[i + 3]) << 16);
    o.z = (unsigned)f2bf(f[i + 4]) | ((unsigned)f2bf(f[i + 5]) << 16);
    o.w = (unsigned)f2bf(f[i + 6]) | ((unsigned)f2bf(f[i + 7]) << 16);
    *(uint4*)(out + i) = o;
  } else {
    *(uint4*)(out + i) = *(const uint4*)((const u16*)in + i);
  }
}

// ------------- output: bf16 scratch -> d_out (fp32 if probe fp32, else bf16) ----------
__global__ __launch_bounds__(256) void out_cvt(const u16* __restrict__ in,
                                               void* __restrict__ out, int n,
                                               const u16* __restrict__ probe) {
  int i = (blockIdx.x * 256 + threadIdx.x) * 8;
  if (i >= n) return;
  uint4 v = *(const uint4*)(in + i);
  if (is_f32(probe)) {
    float* f = (float*)out;
    uint4 a, b;
    a.x = (v.x & 0xffffu) << 16;  a.y = v.x & 0xffff0000u;
    a.z = (v.y & 0xffffu) << 16;  a.w = v.y & 0xffff0000u;
    b.x = (v.z & 0xffffu) << 16;  b.y = v.z & 0xffff0000u;
    b.z = (v.w & 0xffffu) << 16;  b.w = v.w & 0xffff0000u;
    *(uint4*)(f + i) = a;
    *(uint4*)(f + i + 4) = b;
  } else {
    *(uint4*)((u16*)out + i) = v;
  }
}

// ---------- transpose+convert: in (R,C) fp32/bf16 per probe -> out (C,R) bf16 ---------
__global__ __launch_bounds__(256) void transpose_cvt(const void* __restrict__ in,
                                                     u16* __restrict__ out,
                                                     int R, int C,
                                                     const u16* __restrict__ probe) {
  __shared__ u16 tile[32][33];
  int bx = blockIdx.x * 32;  // input col base
  int by = blockIdx.y * 32;  // input row base
  int tx = threadIdx.x & 31, ty = threadIdx.x >> 5;  // 32 x 8
  if (is_f32(probe)) {
    const float* f = (const float*)in;
    for (int i = 0; i < 32; i += 8)
      tile[ty + i][tx] = f2bf(f[(size_t)(by + ty + i) * C + (bx + tx)]);
  } else {
    const u16* u = (const u16*)in;
    for (int i = 0; i < 32; i += 8)
      tile[ty + i][tx] = u[(size_t)(by + ty + i) * C + (bx + tx)];
  }
  __syncthreads();
  for (int i = 0; i < 32; i += 8)
    out[(size_t)(bx + ty + i) * R + (by + tx)] = tile[tx][ty + i];
}

// ---------------- transpose (bf16), batched: in (Z,R,C) -> out (Z,C,R) ----------------
__global__ __launch_bounds__(256) void transpose_bf16(const u16* __restrict__ in,
                                                      u16* __restrict__ out,
                                                      int R, int C) {
  __shared__ u16 tile[32][33];
  size_t base = (size_t)blockIdx.z * R * C;
  int bx = blockIdx.x * 32;
  int by = blockIdx.y * 32;
  int tx = threadIdx.x & 31, ty = threadIdx.x >> 5;
  for (int i = 0; i < 32; i += 8)
    tile[ty + i][tx] = in[base + (size_t)(by + ty + i) * C + (bx + tx)];
  __syncthreads();
  for (int i = 0; i < 32; i += 8)
    out[base + (size_t)(bx + ty + i) * R + (by + tx)] = tile[tx][ty + i];
}

// ---------------- GEMM: C[M,N] = A[M,K] * BT[N,K]^T  (bf16 in, fp32 acc, bf16 out) ----
// 128x128 tile, 256 threads (4 waves, 2x2), BK=32, mfma 16x16x32 bf16,
// global_load_lds width-16 staging (m97 structure). Single instantiation, no branches.
__global__ __launch_bounds__(256) void gemm_bt(const u16* __restrict__ A,
                                               const u16* __restrict__ BT,
                                               u16* __restrict__ C,
                                               int M, int N, int K) {
  __shared__ __align__(16) u16 As[128 * 32];
  __shared__ __align__(16) u16 Bs[128 * 32];
  const int m0 = blockIdx.y * 128, n0 = blockIdx.x * 128;
  const int t = threadIdx.x;
  const int wave = t >> 6, lane = t & 63;
  const int wm = (wave >> 1) * 64, wn = (wave & 1) * 64;
  const int quad = lane >> 4, l16 = lane & 15;
  floatx4 acc[4][4];
  for (int i = 0; i < 4; ++i)
    for (int j = 0; j < 4; ++j) acc[i][j] = (floatx4){0.f, 0.f, 0.f, 0.f};

  for (int kt = 0; kt < K; kt += 32) {
    __syncthreads();
    for (int i = 0; i < 2; ++i) {
      int e = (i * 256 + t) * 8;  // element idx in [row][k] tile, k inner (32); lane-contiguous 16B
      int r = e >> 5, c = e & 31;
      GLOAD_LDS16(A + (size_t)(m0 + r) * K + kt + c, As + e);
      GLOAD_LDS16(BT + (size_t)(n0 + r) * K + kt + c, Bs + e);
    }
    __syncthreads();
    bf16x8 af[4], bfr[4];
    for (int i = 0; i < 4; ++i)
      af[i] = *(const bf16x8*)&As[(wm + i * 16 + l16) * 32 + quad * 8];
    for (int j = 0; j < 4; ++j)
      bfr[j] = *(const bf16x8*)&Bs[(wn + j * 16 + l16) * 32 + quad * 8];
    for (int i = 0; i < 4; ++i)
      for (int j = 0; j < 4; ++j)
        acc[i][j] = __builtin_amdgcn_mfma_f32_16x16x32_bf16(af[i], bfr[j], acc[i][j], 0, 0, 0);
  }
  // epilogue: C row = quad*4+reg, col = l16 (verified m89/m91 layout)
  for (int i = 0; i < 4; ++i) {
    int rbase = m0 + wm + i * 16 + quad * 4;
    for (int j = 0; j < 4; ++j) {
      int col = n0 + wn + j * 16 + l16;
      for (int r = 0; r < 4; ++r)
        C[(size_t)(rbase + r) * N + col] = f2bf(acc[i][j][r]);
    }
  }
}

// ---------------- RMSNorm over rows of 512, in place (bf16) ---------------------------
__global__ __launch_bounds__(256) void rmsnorm_kernel(u16* __restrict__ t,
                                                      const u16* __restrict__ w) {
  int row = blockIdx.x * 4 + (threadIdx.x >> 6);
  int lane = threadIdx.x & 63;
  u16* xr = t + (size_t)row * 512;
  float v[8];
  float ss = 0.f;
  for (int i = 0; i < 8; ++i) {
    v[i] = bf2f(xr[lane + i * 64]);
    ss += v[i] * v[i];
  }
  for (int d = 32; d > 0; d >>= 1) ss += __shfl_xor(ss, d);
  float r = rsqrtf(ss * (1.f / 512.f) + 1e-6f);
  for (int i = 0; i < 8; ++i) xr[lane + i * 64] = f2bf(v[i] * r * bf2f(w[lane + i * 64]));
}

// ---------------- RoPE, interleaved pairs, in-place. t: (B,S,16,128) bf16 -------------
__global__ __launch_bounds__(256) void rope_kernel(u16* __restrict__ t,
                                                   const u16* __restrict__ fc,
                                                   const u16* __restrict__ fs) {
  unsigned int idx = blockIdx.x * 256 + threadIdx.x;  // pair idx: p[5:0] h[9:6] s[20:10] b[21]
  int p = idx & 63;
  int s = (idx >> 10) & 2047;
  unsigned int pk = *(const unsigned int*)(t + (size_t)idx * 2);
  float x1 = bf2f((u16)(pk & 0xffffu));
  float x2 = bf2f((u16)(pk >> 16));
  float c = bf2f(fc[s * 64 + p]);
  float sv = bf2f(fs[s * 64 + p]);
  float o1 = x1 * c - x2 * sv;
  float o2 = x1 * sv + x2 * c;
  unsigned int ou = (unsigned int)f2bf(o1) | ((unsigned int)f2bf(o2) << 16);
  *(unsigned int*)(t + (size_t)idx * 2) = ou;
}

// ---------------- Flash attention (causal), bf16 MFMA, fp32 softmax -------------------
// q,k: (B,S,H*128) post-RoPE.  vt: (B,H,128,S).  o: (B,S,H*128).
// Block = 4 waves sharing one (qb,bh): wave w owns q rows q0=qb*64+w*16.
// K-tile (64x128) and V-tile (128x64) staged in LDS via global_load_lds with
// source-granule XOR swizzle (LDS dest stays lane-linear per the wave-uniform
// contract); fragment ds_read_b128 lands 2-way-conflict max (free per m136).
__global__ __launch_bounds__(256) void attn_kernel(const u16* __restrict__ q,
                                                   const u16* __restrict__ k,
                                                   const u16* __restrict__ vt,
                                                   u16* __restrict__ o) {
  const int S = 2048;
  __shared__ __align__(16) u16 Kt[64 * 128];   // [key][chunk8 ^ (key&15)]
  __shared__ __align__(16) u16 Vt[128 * 64];   // [d][granule8 ^ (d&7)]
  __shared__ __align__(16) u16 P[4][16][72];   // +8 pad: pa reads 2-way max
  const int t = threadIdx.x;
  const int w = t >> 6, lane = t & 63;
  const int quad = lane >> 4, l16 = lane & 15;
  const int bh = blockIdx.x;
  const int b = bh >> 4, h = bh & 15;
  const int qb = (int)gridDim.y - 1 - (int)blockIdx.y;  // heaviest first
  const int q0 = qb * 64 + w * 16;
  const float scale = 0.08838834764831845f;  // 1/sqrt(128)

  // Q fragments (A layout: m=l16, k=quad*8+j), 4 dim-chunks of 32
  const u16* qbase = q + ((size_t)(b * S + q0 + l16)) * 2048 + h * 128;
  bf16x8 qf[4];
  for (int c = 0; c < 4; ++c) qf[c] = *(const bf16x8*)(qbase + c * 32 + quad * 8);

  const u16* kbase = k + (size_t)b * S * 2048 + h * 128;
  const u16* vtb = vt + (size_t)bh * 128 * S;

  // K staging decode: issue j covers keys j*16 + (t>>4); 16 chunks of 8 per key row
  const int ksrow = t >> 4, ksc = t & 15;
  // V staging decode: issue j covers dims j*32 + (t>>3); 8 granules of 8 per dim row
  const int vsrow = t >> 3, vsc = t & 7;

  float m_i[4], l_i[4];
  floatx4 acc[8];
  for (int r = 0; r < 4; ++r) { m_i[r] = -1e30f; l_i[r] = 0.f; }
  for (int nd = 0; nd < 8; ++nd) acc[nd] = (floatx4){0.f, 0.f, 0.f, 0.f};

  const int kmax = q0 + 15;  // last unmasked key for this wave
  for (int kb = 0; kb <= qb * 64; kb += 64) {
    __syncthreads();  // all waves done reading Kt/Vt from previous step
    for (int j = 0; j < 4; ++j) {
      int row = j * 16 + ksrow;
      GLOAD_LDS16(kbase + (size_t)(kb + row) * 2048 + (ksc ^ (row & 15)) * 8,
                  Kt + (size_t)(row * 16 + ksc) * 8);
    }
    for (int j = 0; j < 4; ++j) {
      int row = j * 32 + vsrow;
      GLOAD_LDS16(vtb + (size_t)row * S + kb + ((vsc ^ (row & 7)) * 8),
                  Vt + (size_t)(row * 8 + vsc) * 8);
    }
    __syncthreads();  // staging drained

    // ---- scores (skip fully-masked 16-key sub-blocks on the diagonal step) ----
    floatx4 s[4];
    for (int ns = 0; ns < 4; ++ns) {
      if (kb + ns * 16 <= kmax) {
        s[ns] = (floatx4){0.f, 0.f, 0.f, 0.f};
        for (int c = 0; c < 4; ++c) {
          bf16x8 kf = *(const bf16x8*)&Kt[(ns * 16 + l16) * 128 + ((c * 4 + quad) ^ l16) * 8];
          s[ns] = __builtin_amdgcn_mfma_f32_16x16x32_bf16(qf[c], kf, s[ns], 0, 0, 0);
        }
        int key = kb + ns * 16 + l16;
        for (int r = 0; r < 4; ++r) {
          float x = s[ns][r] * scale;
          s[ns][r] = (key > q0 + quad * 4 + r) ? -1e30f : x;
        }
      } else {
        s[ns] = (floatx4){-1e30f, -1e30f, -1e30f, -1e30f};
      }
    }
    // ---- online softmax (16-lane butterfly; score row = quad*4+r, col = l16) ----
    float alpha[4];
    for (int r = 0; r < 4; ++r) {
      float v = fmaxf(fmaxf(s[0][r], s[1][r]), fmaxf(s[2][r], s[3][r]));
      for (int d = 1; d < 16; d <<= 1) v = fmaxf(v, __shfl_xor(v, d));
      float mn = fmaxf(m_i[r], v);
      alpha[r] = __expf(m_i[r] - mn);
      m_i[r] = mn;
    }
    for (int ns = 0; ns < 4; ++ns)
      for (int r = 0; r < 4; ++r) s[ns][r] = __expf(s[ns][r] - m_i[r]);
    for (int r = 0; r < 4; ++r) {
      float v = s[0][r] + s[1][r] + s[2][r] + s[3][r];
      for (int d = 1; d < 16; d <<= 1) v += __shfl_xor(v, d);
      l_i[r] = l_i[r] * alpha[r] + v;
    }
    for (int nd = 0; nd < 8; ++nd)
      for (int r = 0; r < 4; ++r) acc[nd][r] *= alpha[r];
    // ---- P to LDS (C layout -> A layout; per-wave private, no barrier needed) ----
    for (int ns = 0; ns < 4; ++ns)
      for (int r = 0; r < 4; ++r) P[w][quad * 4 + r][ns * 16 + l16] = f2bf(s[ns][r]);
    // ---- PV: O += P(16x64) * V(64x128), V frags from swizzled LDS ----
    for (int kc = 0; kc < 2; ++kc) {
      if (kb + kc * 32 <= kmax) {
        bf16x8 pa = *(const bf16x8*)&P[w][l16][kc * 32 + quad * 8];
        for (int nd = 0; nd < 8; ++nd) {
          int d = nd * 16 + l16;
          bf16x8 vf = *(const bf16x8*)&Vt[(d * 8 + ((kc * 4 + quad) ^ (d & 7))) * 8];
          acc[nd] = __builtin_amdgcn_mfma_f32_16x16x32_bf16(pa, vf, acc[nd], 0, 0, 0);
        }
      }
    }
  }
  // ---- epilogue ----
  u16* ob = o + ((size_t)(b * S + q0 + quad * 4)) * 2048 + h * 128;
  for (int r = 0; r < 4; ++r) {
    float inv = 1.f / l_i[r];
    for (int nd = 0; nd < 8; ++nd)
      ob[(size_t)r * 2048 + nd * 16 + l16] = f2bf(acc[nd][r] * inv);
  }
}

// ------------------------------------ launcher ---------------------------------------
// Workspace: 83 MiB, lifetime-aliased. Input dtype (fp32 vs bf16) detected on-device
// from freqs_cos[0] (fp32 1.0f low u16 == 0x0000; bf16 1.0 == 0x3F80).
extern "C" void kernel_launch(void* const* d_in, const int* in_sizes, int n_in,
                              void* d_out, int out_size, void* d_ws, size_t ws_size,
                              hipStream_t stream) {
  const void* x    = d_in[0];  // (2,2048,2048)
  const void* fcos = d_in[1];  // (2048,64)
  const void* fsin = d_in[2];
  const void* wkv  = d_in[3];  // (2048,512)
  const void* wnr  = d_in[4];  // (512,)
  const void* wku  = d_in[5];  // (512,2048)
  const void* wvu  = d_in[6];  // (512,2048)
  const void* wq   = d_in[7];  // (2048,2048)
  const void* wo   = d_in[8];  // (2048,2048)
  const u16* probe = (const u16*)fcos;

  const size_t MB = 1u << 20;
  char* ws = (char*)d_ws;
  u16* xc    = (u16*)(ws);             // 16 MiB x in bf16; dead after gemmQ+gemmKV
  u16* vtb   = (u16*)(ws);             //   ... then V^T (B,H,128,S)
  u16* qb    = (u16*)(ws + 16 * MB);   // 16 MiB q; dead after attn -> final gemm out
  u16* ob2   = (u16*)(ws + 16 * MB);   //   ... bf16 staging for d_out
  u16* kb    = (u16*)(ws + 32 * MB);   // 16 MiB
  u16* vb    = (u16*)(ws + 48 * MB);   // 16 MiB V; dead after transposeV
  u16* ab    = (u16*)(ws + 48 * MB);   //   ... then attention output
  u16* lat   = (u16*)(ws + 64 * MB);   // 4 MiB
  u16* wqT   = (u16*)(ws + 68 * MB);   // 8 MiB; dead after gemmQ
  u16* woT   = (u16*)(ws + 68 * MB);   //   ... then w_out^T
  u16* wkvT  = (u16*)(ws + 76 * MB);   // 2 MiB
  u16* wkT   = (u16*)(ws + 78 * MB);   // 2 MiB
  u16* wvT   = (u16*)(ws + 80 * MB);   // 2 MiB
  u16* fcosc = (u16*)(ws + 82 * MB);   // 256 KiB
  u16* fsinc = (u16*)(ws + 82 * MB + 256 * 1024);
  u16* wnrc  = (u16*)(ws + 82 * MB + 512 * 1024);  // 1 KiB  (total < 83 MiB)

  dim3 blk(256);
  // --- convert inputs to bf16 (identity copy if already bf16) ---
  cvt_to_bf16<<<dim3(4096), blk, 0, stream>>>(x, xc, 8388608, probe);
  cvt_to_bf16<<<dim3(64), blk, 0, stream>>>(fcos, fcosc, 131072, probe);
  cvt_to_bf16<<<dim3(64), blk, 0, stream>>>(fsin, fsinc, 131072, probe);
  cvt_to_bf16<<<dim3(1), blk, 0, stream>>>(wnr, wnrc, 512, probe);

  // --- Q path ---
  transpose_cvt<<<dim3(64, 64), blk, 0, stream>>>(wq, wqT, 2048, 2048, probe);
  gemm_bt<<<dim3(16, 32), blk, 0, stream>>>(xc, wqT, qb, 4096, 2048, 2048);
  rope_kernel<<<dim3(16384), blk, 0, stream>>>(qb, fcosc, fsinc);

  // --- KV latent ---
  transpose_cvt<<<dim3(16, 64), blk, 0, stream>>>(wkv, wkvT, 2048, 512, probe);
  gemm_bt<<<dim3(4, 32), blk, 0, stream>>>(xc, wkvT, lat, 4096, 512, 2048);
  rmsnorm_kernel<<<dim3(1024), blk, 0, stream>>>(lat, wnrc);

  // --- K, V up-projections ---
  transpose_cvt<<<dim3(64, 16), blk, 0, stream>>>(wku, wkT, 512, 2048, probe);
  gemm_bt<<<dim3(16, 32), blk, 0, stream>>>(lat, wkT, kb, 4096, 2048, 512);
  rope_kernel<<<dim3(16384), blk, 0, stream>>>(kb, fcosc, fsinc);
  transpose_cvt<<<dim3(64, 16), blk, 0, stream>>>(wvu, wvT, 512, 2048, probe);
  gemm_bt<<<dim3(16, 32), blk, 0, stream>>>(lat, wvT, vb, 4096, 2048, 512);

  // --- V -> (B,H,128,S); xc dead by now. w_out^T into dead wqT slot ---
  transpose_bf16<<<dim3(64, 64, 2), blk, 0, stream>>>(vb, vtb, 2048, 2048);
  transpose_cvt<<<dim3(64, 64), blk, 0, stream>>>(wo, woT, 2048, 2048, probe);

  // --- causal flash attention (ab aliases dead vb; x=bh, y=qb reversed) ---
  attn_kernel<<<dim3(32, 32), blk, 0, stream>>>(qb, kb, vtb, ab);

  // --- output projection into bf16 scratch (qb dead), then dtype-cast to d_out ---
  gemm_bt<<<dim3(16, 32), blk, 0, stream>>>(ab, woT, ob2, 4096, 2048, 2048);
  out_cvt<<<dim3(4096), blk, 0, stream>>>(ob2, d_out, 8388608, probe);
}

// Round 6
// 446.351 us; speedup vs baseline: 2.5341x; 1.0409x over previous
//
#include <hip/hip_runtime.h>

typedef unsigned short u16;
typedef __attribute__((ext_vector_type(8))) short bf16x8;   // 8 bf16 = 4 VGPRs (MFMA A/B frag)
typedef __attribute__((ext_vector_type(4))) float floatx4;  // MFMA C/D frag

__device__ __forceinline__ float bf2f(u16 h) {
  return __uint_as_float(((unsigned int)h) << 16);
}
__device__ __forceinline__ u16 f2bf(float f) {
  unsigned int u = __float_as_uint(f);
  u += 0x7fffu + ((u >> 16) & 1u);  // RNE
  return (u16)(u >> 16);
}
// probe[0] is freqs_cos[0] == 1.0f: fp32 low u16 = 0x0000, bf16 = 0x3F80.
__device__ __forceinline__ bool is_f32(const u16* probe) { return probe[0] == 0; }

// async global->LDS, 16B per lane. LDS dest must be wave-uniform base + lane*16.
#define GLOAD_LDS16(gsrc, ldst)                                                        \
  __builtin_amdgcn_global_load_lds(                                                    \
      (const __attribute__((address_space(1))) unsigned int*)(gsrc),                   \
      (__attribute__((address_space(3))) unsigned int*)(ldst), 16, 0, 0)

// ------------- convert any input buffer (fp32 or bf16 per probe) -> bf16 --------------
__global__ __launch_bounds__(256) void cvt_to_bf16(const void* __restrict__ in,
                                                   u16* __restrict__ out, int n,
                                                   const u16* __restrict__ probe) {
  int i = (blockIdx.x * 256 + threadIdx.x) * 8;
  if (i >= n) return;
  if (is_f32(probe)) {
    const float* f = (const float*)in;
    uint4 o;
    o.x = (unsigned)f2bf(f[i + 0]) | ((unsigned)f2bf(f[i + 1]) << 16);
    o.y = (unsigned)f2bf(f[i + 2]) | ((unsigned)f2bf(f[i + 3]) << 16);
    o.z = (unsigned)f2bf(f[i + 4]) | ((unsigned)f2bf(f[i + 5]) << 16);
    o.w = (unsigned)f2bf(f[i + 6]) | ((unsigned)f2bf(f[i + 7]) << 16);
    *(uint4*)(out + i) = o;
  } else {
    *(uint4*)(out + i) = *(const uint4*)((const u16*)in + i);
  }
}

// ------------- output: bf16 scratch -> d_out (fp32 if probe fp32, else bf16) ----------
__global__ __launch_bounds__(256) void out_cvt(const u16* __restrict__ in,
                                               void* __restrict__ out, int n,
                                               const u16* __restrict__ probe) {
  int i = (blockIdx.x * 256 + threadIdx.x) * 8;
  if (i >= n) return;
  uint4 v = *(const uint4*)(in + i);
  if (is_f32(probe)) {
    float* f = (float*)out;
    uint4 a, b;
    a.x = (v.x & 0xffffu) << 16;  a.y = v.x & 0xffff0000u;
    a.z = (v.y & 0xffffu) << 16;  a.w = v.y & 0xffff0000u;
    b.x = (v.z & 0xffffu) << 16;  b.y = v.z & 0xffff0000u;
    b.z = (v.w & 0xffffu) << 16;  b.w = v.w & 0xffff0000u;
    *(uint4*)(f + i) = a;
    *(uint4*)(f + i + 4) = b;
  } else {
    *(uint4*)((u16*)out + i) = v;
  }
}

// ---------- transpose+convert: in (R,C) fp32/bf16 per probe -> out (C,R) bf16 ---------
__global__ __launch_bounds__(256) void transpose_cvt(const void* __restrict__ in,
                                                     u16* __restrict__ out,
                                                     int R, int C,
                                                     const u16* __restrict__ probe) {
  __shared__ u16 tile[32][33];
  int bx = blockIdx.x * 32;  // input col base
  int by = blockIdx.y * 32;  // input row base
  int tx = threadIdx.x & 31, ty = threadIdx.x >> 5;  // 32 x 8
  if (is_f32(probe)) {
    const float* f = (const float*)in;
    for (int i = 0; i < 32; i += 8)
      tile[ty + i][tx] = f2bf(f[(size_t)(by + ty + i) * C + (bx + tx)]);
  } else {
    const u16* u = (const u16*)in;
    for (int i = 0; i < 32; i += 8)
      tile[ty + i][tx] = u[(size_t)(by + ty + i) * C + (bx + tx)];
  }
  __syncthreads();
  for (int i = 0; i < 32; i += 8)
    out[(size_t)(bx + ty + i) * R + (by + tx)] = tile[tx][ty + i];
}

// ---------------- transpose (bf16), batched: in (Z,R,C) -> out (Z,C,R) ----------------
__global__ __launch_bounds__(256) void transpose_bf16(const u16* __restrict__ in,
                                                      u16* __restrict__ out,
                                                      int R, int C) {
  __shared__ u16 tile[32][33];
  size_t base = (size_t)blockIdx.z * R * C;
  int bx = blockIdx.x * 32;
  int by = blockIdx.y * 32;
  int tx = threadIdx.x & 31, ty = threadIdx.x >> 5;
  for (int i = 0; i < 32; i += 8)
    tile[ty + i][tx] = in[base + (size_t)(by + ty + i) * C + (bx + tx)];
  __syncthreads();
  for (int i = 0; i < 32; i += 8)
    out[base + (size_t)(bx + ty + i) * R + (by + tx)] = tile[tx][ty + i];
}

// ---------------- GEMM: C[M,N] = A[M,K] * BT[N,K]^T  (bf16 in, fp32 acc, bf16 out) ----
// 128x128 tile, 256 threads (4 waves, 2x2), BK=32, mfma 16x16x32 bf16,
// global_load_lds width-16 staging (m97 structure).
__global__ __launch_bounds__(256) void gemm_bt(const u16* __restrict__ A,
                                               const u16* __restrict__ BT,
                                               u16* __restrict__ C,
                                               int M, int N, int K) {
  __shared__ __align__(16) u16 As[128 * 32];
  __shared__ __align__(16) u16 Bs[128 * 32];
  const int m0 = blockIdx.y * 128, n0 = blockIdx.x * 128;
  const int t = threadIdx.x;
  const int wave = t >> 6, lane = t & 63;
  const int wm = (wave >> 1) * 64, wn = (wave & 1) * 64;
  const int quad = lane >> 4, l16 = lane & 15;
  floatx4 acc[4][4];
  for (int i = 0; i < 4; ++i)
    for (int j = 0; j < 4; ++j) acc[i][j] = (floatx4){0.f, 0.f, 0.f, 0.f};

  for (int kt = 0; kt < K; kt += 32) {
    __syncthreads();
    for (int i = 0; i < 2; ++i) {
      int e = (i * 256 + t) * 8;  // [row][k] tile, k inner (32); lane-contiguous 16B
      int r = e >> 5, c = e & 31;
      GLOAD_LDS16(A + (size_t)(m0 + r) * K + kt + c, As + e);
      GLOAD_LDS16(BT + (size_t)(n0 + r) * K + kt + c, Bs + e);
    }
    __syncthreads();
    bf16x8 af[4], bfr[4];
    for (int i = 0; i < 4; ++i)
      af[i] = *(const bf16x8*)&As[(wm + i * 16 + l16) * 32 + quad * 8];
    for (int j = 0; j < 4; ++j)
      bfr[j] = *(const bf16x8*)&Bs[(wn + j * 16 + l16) * 32 + quad * 8];
    for (int i = 0; i < 4; ++i)
      for (int j = 0; j < 4; ++j)
        acc[i][j] = __builtin_amdgcn_mfma_f32_16x16x32_bf16(af[i], bfr[j], acc[i][j], 0, 0, 0);
  }
  // epilogue: C row = quad*4+reg, col = l16 (verified m89/m91 layout)
  for (int i = 0; i < 4; ++i) {
    int rbase = m0 + wm + i * 16 + quad * 4;
    for (int j = 0; j < 4; ++j) {
      int col = n0 + wn + j * 16 + l16;
      for (int r = 0; r < 4; ++r)
        C[(size_t)(rbase + r) * N + col] = f2bf(acc[i][j][r]);
    }
  }
}

// ------------- GEMM + fused interleaved RoPE (+ output scale) on all columns ----------
// Same body as gemm_bt; epilogue applies rope via __shfl_xor(v,1) pair exchange:
// col pairs (2p,2p+1) live in adjacent lanes (l16 even/odd). token s = row & 2047,
// pair p = ((wn + j*16 + l16) >> 1) (col within head /2; n0 multiple of 128 drops out).
__global__ __launch_bounds__(256) void gemm_rope(const u16* __restrict__ A,
                                                 const u16* __restrict__ BT,
                                                 u16* __restrict__ C,
                                                 int M, int N, int K,
                                                 const u16* __restrict__ fc,
                                                 const u16* __restrict__ fs,
                                                 float oscale) {
  __shared__ __align__(16) u16 As[128 * 32];
  __shared__ __align__(16) u16 Bs[128 * 32];
  const int m0 = blockIdx.y * 128, n0 = blockIdx.x * 128;
  const int t = threadIdx.x;
  const int wave = t >> 6, lane = t & 63;
  const int wm = (wave >> 1) * 64, wn = (wave & 1) * 64;
  const int quad = lane >> 4, l16 = lane & 15;
  floatx4 acc[4][4];
  for (int i = 0; i < 4; ++i)
    for (int j = 0; j < 4; ++j) acc[i][j] = (floatx4){0.f, 0.f, 0.f, 0.f};

  for (int kt = 0; kt < K; kt += 32) {
    __syncthreads();
    for (int i = 0; i < 2; ++i) {
      int e = (i * 256 + t) * 8;
      int r = e >> 5, c = e & 31;
      GLOAD_LDS16(A + (size_t)(m0 + r) * K + kt + c, As + e);
      GLOAD_LDS16(BT + (size_t)(n0 + r) * K + kt + c, Bs + e);
    }
    __syncthreads();
    bf16x8 af[4], bfr[4];
    for (int i = 0; i < 4; ++i)
      af[i] = *(const bf16x8*)&As[(wm + i * 16 + l16) * 32 + quad * 8];
    for (int j = 0; j < 4; ++j)
      bfr[j] = *(const bf16x8*)&Bs[(wn + j * 16 + l16) * 32 + quad * 8];
    for (int i = 0; i < 4; ++i)
      for (int j = 0; j < 4; ++j)
        acc[i][j] = __builtin_amdgcn_mfma_f32_16x16x32_bf16(af[i], bfr[j], acc[i][j], 0, 0, 0);
  }
  const bool odd = (l16 & 1);  // odd col of the rope pair
  for (int i = 0; i < 4; ++i) {
    int rbase = m0 + wm + i * 16 + quad * 4;
    for (int j = 0; j < 4; ++j) {
      int col = n0 + wn + j * 16 + l16;
      int p = (wn + j * 16 + l16) >> 1;  // pair index within head (0..63)
      for (int r = 0; r < 4; ++r) {
        int srow = (rbase + r) & 2047;  // token index (M = B*2048)
        float c = bf2f(fc[srow * 64 + p]);
        float sn = bf2f(fs[srow * 64 + p]);
        float v = acc[i][j][r];
        float pv = __shfl_xor(v, 1);
        // even col: o = v*c - pv*sn ; odd col: o = pv*sn + v*c
        float o = fmaf(v, c, odd ? pv * sn : -pv * sn);
        C[(size_t)(rbase + r) * N + col] = f2bf(o * oscale);
      }
    }
  }
}

// ---------------- RMSNorm over rows of 512, in place (bf16) ---------------------------
__global__ __launch_bounds__(256) void rmsnorm_kernel(u16* __restrict__ t,
                                                      const u16* __restrict__ w) {
  int row = blockIdx.x * 4 + (threadIdx.x >> 6);
  int lane = threadIdx.x & 63;
  u16* xr = t + (size_t)row * 512;
  float v[8];
  float ss = 0.f;
  for (int i = 0; i < 8; ++i) {
    v[i] = bf2f(xr[lane + i * 64]);
    ss += v[i] * v[i];
  }
  for (int d = 32; d > 0; d >>= 1) ss += __shfl_xor(ss, d);
  float r = rsqrtf(ss * (1.f / 512.f) + 1e-6f);
  for (int i = 0; i < 8; ++i) xr[lane + i * 64] = f2bf(v[i] * r * bf2f(w[lane + i * 64]));
}

// ---------------- Flash attention (causal), bf16 MFMA, fp32 softmax -------------------
// q (PRE-SCALED by 1/sqrt(128) in gemm_rope), k: (B,S,H*128).  vt: (B,H,128,S).
// o: (B,S,H*128). Block = 4 waves sharing (qb,bh); wave w owns rows q0=qb*64+w*16.
// K-tile (64x128) + V-tile (128x64) staged via global_load_lds with source-granule
// XOR swizzle; P is granule-XOR swizzled at stride 64 -> LDS total exactly 40 KiB
// (4 blocks/CU). Mask/guards only on the diagonal step (uniform branch).
__global__ __launch_bounds__(256) void attn_kernel(const u16* __restrict__ q,
                                                   const u16* __restrict__ k,
                                                   const u16* __restrict__ vt,
                                                   u16* __restrict__ o) {
  const int S = 2048;
  __shared__ __align__(16) u16 Kt[64 * 128];   // [key][chunk8 ^ (key&15)]
  __shared__ __align__(16) u16 Vt[128 * 64];   // [d][granule8 ^ (d&7)]
  __shared__ __align__(16) u16 P[4][16][64];   // [row][granule8 ^ (row&7)]
  const int t = threadIdx.x;
  const int w = t >> 6, lane = t & 63;
  const int quad = lane >> 4, l16 = lane & 15;
  const int bh = blockIdx.x;
  const int b = bh >> 4, h = bh & 15;
  const int qb = (int)gridDim.y - 1 - (int)blockIdx.y;  // heaviest first
  const int q0 = qb * 64 + w * 16;

  // Q fragments (A layout: m=l16, k=quad*8+j), 4 dim-chunks of 32
  const u16* qbase = q + ((size_t)(b * S + q0 + l16)) * 2048 + h * 128;
  bf16x8 qf[4];
  for (int c = 0; c < 4; ++c) qf[c] = *(const bf16x8*)(qbase + c * 32 + quad * 8);

  const u16* kbase = k + (size_t)b * S * 2048 + h * 128;
  const u16* vtb = vt + (size_t)bh * 128 * S;

  const int ksrow = t >> 4, ksc = t & 15;  // K staging decode
  const int vsrow = t >> 3, vsc = t & 7;   // V staging decode

  float m_i[4], l_i[4];
  floatx4 acc[8];
  for (int r = 0; r < 4; ++r) { m_i[r] = -1e30f; l_i[r] = 0.f; }
  for (int nd = 0; nd < 8; ++nd) acc[nd] = (floatx4){0.f, 0.f, 0.f, 0.f};

  const int kmax = q0 + 15;      // last unmasked key for this wave
  const int qbase64 = qb * 64;   // diagonal step base
  for (int kb = 0; kb <= qbase64; kb += 64) {
    const bool diag = (kb == qbase64);
    __syncthreads();  // all waves done reading Kt/Vt from previous step
    for (int j = 0; j < 4; ++j) {
      int row = j * 16 + ksrow;
      GLOAD_LDS16(kbase + (size_t)(kb + row) * 2048 + (ksc ^ (row & 15)) * 8,
                  Kt + (size_t)(row * 16 + ksc) * 8);
    }
    for (int j = 0; j < 4; ++j) {
      int row = j * 32 + vsrow;
      GLOAD_LDS16(vtb + (size_t)row * S + kb + ((vsc ^ (row & 7)) * 8),
                  Vt + (size_t)(row * 8 + vsc) * 8);
    }
    __syncthreads();  // staging drained

    // ---- scores (Q pre-scaled; masks only on diagonal step) ----
    floatx4 s[4];
    if (!diag) {
      for (int ns = 0; ns < 4; ++ns) {
        s[ns] = (floatx4){0.f, 0.f, 0.f, 0.f};
        for (int c = 0; c < 4; ++c) {
          bf16x8 kf = *(const bf16x8*)&Kt[(ns * 16 + l16) * 128 + ((c * 4 + quad) ^ l16) * 8];
          s[ns] = __builtin_amdgcn_mfma_f32_16x16x32_bf16(qf[c], kf, s[ns], 0, 0, 0);
        }
      }
    } else {
      for (int ns = 0; ns < 4; ++ns) {
        if (kb + ns * 16 <= kmax) {
          s[ns] = (floatx4){0.f, 0.f, 0.f, 0.f};
          for (int c = 0; c < 4; ++c) {
            bf16x8 kf = *(const bf16x8*)&Kt[(ns * 16 + l16) * 128 + ((c * 4 + quad) ^ l16) * 8];
            s[ns] = __builtin_amdgcn_mfma_f32_16x16x32_bf16(qf[c], kf, s[ns], 0, 0, 0);
          }
          int key = kb + ns * 16 + l16;
          for (int r = 0; r < 4; ++r)
            s[ns][r] = (key > q0 + quad * 4 + r) ? -1e30f : s[ns][r];
        } else {
          s[ns] = (floatx4){-1e30f, -1e30f, -1e30f, -1e30f};
        }
      }
    }
    // ---- online softmax (16-lane butterfly; score row = quad*4+r, col = l16) ----
    float alpha[4];
    for (int r = 0; r < 4; ++r) {
      float v = fmaxf(fmaxf(s[0][r], s[1][r]), fmaxf(s[2][r], s[3][r]));
      for (int d = 1; d < 16; d <<= 1) v = fmaxf(v, __shfl_xor(v, d));
      float mn = fmaxf(m_i[r], v);
      alpha[r] = __expf(m_i[r] - mn);
      m_i[r] = mn;
    }
    for (int ns = 0; ns < 4; ++ns)
      for (int r = 0; r < 4; ++r) s[ns][r] = __expf(s[ns][r] - m_i[r]);
    for (int r = 0; r < 4; ++r) {
      float v = s[0][r] + s[1][r] + s[2][r] + s[3][r];
      for (int d = 1; d < 16; d <<= 1) v += __shfl_xor(v, d);
      l_i[r] = l_i[r] * alpha[r] + v;
    }
    for (int nd = 0; nd < 8; ++nd)
      for (int r = 0; r < 4; ++r) acc[nd][r] *= alpha[r];
    // ---- P to LDS (C layout -> A layout; swizzled granules; per-wave private) ----
    for (int ns = 0; ns < 4; ++ns)
      for (int r = 0; r < 4; ++r) {
        int row = quad * 4 + r;
        P[w][row][(((ns * 2 + (l16 >> 3)) ^ (row & 7)) << 3) | (l16 & 7)] = f2bf(s[ns][r]);
      }
    // ---- PV: O += P(16x64) * V(64x128), both operands from swizzled LDS ----
    for (int kc = 0; kc < 2; ++kc) {
      if (!diag || kb + kc * 32 <= kmax) {
        bf16x8 pa = *(const bf16x8*)&P[w][l16][((kc * 4 + quad) ^ (l16 & 7)) * 8];
        for (int nd = 0; nd < 8; ++nd) {
          int d = nd * 16 + l16;
          bf16x8 vf = *(const bf16x8*)&Vt[(d * 8 + ((kc * 4 + quad) ^ (d & 7))) * 8];
          acc[nd] = __builtin_amdgcn_mfma_f32_16x16x32_bf16(pa, vf, acc[nd], 0, 0, 0);
        }
      }
    }
  }
  // ---- epilogue ----
  u16* ob = o + ((size_t)(b * S + q0 + quad * 4)) * 2048 + h * 128;
  for (int r = 0; r < 4; ++r) {
    float inv = 1.f / l_i[r];
    for (int nd = 0; nd < 8; ++nd)
      ob[(size_t)r * 2048 + nd * 16 + l16] = f2bf(acc[nd][r] * inv);
  }
}

// ------------------------------------ launcher ---------------------------------------
// Workspace: 83 MiB, lifetime-aliased. Input dtype (fp32 vs bf16) detected on-device
// from freqs_cos[0] (fp32 1.0f low u16 == 0x0000; bf16 1.0 == 0x3F80).
extern "C" void kernel_launch(void* const* d_in, const int* in_sizes, int n_in,
                              void* d_out, int out_size, void* d_ws, size_t ws_size,
                              hipStream_t stream) {
  const void* x    = d_in[0];  // (2,2048,2048)
  const void* fcos = d_in[1];  // (2048,64)
  const void* fsin = d_in[2];
  const void* wkv  = d_in[3];  // (2048,512)
  const void* wnr  = d_in[4];  // (512,)
  const void* wku  = d_in[5];  // (512,2048)
  const void* wvu  = d_in[6];  // (512,2048)
  const void* wq   = d_in[7];  // (2048,2048)
  const void* wo   = d_in[8];  // (2048,2048)
  const u16* probe = (const u16*)fcos;

  const size_t MB = 1u << 20;
  char* ws = (char*)d_ws;
  u16* xc    = (u16*)(ws);             // 16 MiB x bf16; dead after gemmQ+gemmKV
  u16* vtb   = (u16*)(ws);             //   ... then V^T (B,H,128,S)
  u16* qb    = (u16*)(ws + 16 * MB);   // 16 MiB q; dead after attn
  u16* ob2   = (u16*)(ws + 16 * MB);   //   ... bf16 staging for d_out
  u16* kb    = (u16*)(ws + 32 * MB);   // 16 MiB
  u16* vb    = (u16*)(ws + 48 * MB);   // 16 MiB V; dead after transposeV
  u16* ab    = (u16*)(ws + 48 * MB);   //   ... then attention output
  u16* lat   = (u16*)(ws + 64 * MB);   // 4 MiB
  u16* wqT   = (u16*)(ws + 68 * MB);   // 8 MiB; dead after gemmQ
  u16* woT   = (u16*)(ws + 68 * MB);   //   ... then w_out^T
  u16* wkvT  = (u16*)(ws + 76 * MB);   // 2 MiB
  u16* wkT   = (u16*)(ws + 78 * MB);   // 2 MiB
  u16* wvT   = (u16*)(ws + 80 * MB);   // 2 MiB
  u16* fcosc = (u16*)(ws + 82 * MB);   // 256 KiB
  u16* fsinc = (u16*)(ws + 82 * MB + 256 * 1024);
  u16* wnrc  = (u16*)(ws + 82 * MB + 512 * 1024);  // 1 KiB  (total < 83 MiB)

  const float SCALE = 0.08838834764831845f;  // 1/sqrt(128), folded into Q
  dim3 blk(256);
  // --- convert inputs to bf16 (identity copy if already bf16) ---
  cvt_to_bf16<<<dim3(4096), blk, 0, stream>>>(x, xc, 8388608, probe);
  cvt_to_bf16<<<dim3(64), blk, 0, stream>>>(fcos, fcosc, 131072, probe);
  cvt_to_bf16<<<dim3(64), blk, 0, stream>>>(fsin, fsinc, 131072, probe);
  cvt_to_bf16<<<dim3(1), blk, 0, stream>>>(wnr, wnrc, 512, probe);

  // --- Q path: gemm with fused RoPE + softmax scale ---
  transpose_cvt<<<dim3(64, 64), blk, 0, stream>>>(wq, wqT, 2048, 2048, probe);
  gemm_rope<<<dim3(16, 32), blk, 0, stream>>>(xc, wqT, qb, 4096, 2048, 2048,
                                              fcosc, fsinc, SCALE);

  // --- KV latent ---
  transpose_cvt<<<dim3(16, 64), blk, 0, stream>>>(wkv, wkvT, 2048, 512, probe);
  gemm_bt<<<dim3(4, 32), blk, 0, stream>>>(xc, wkvT, lat, 4096, 512, 2048);
  rmsnorm_kernel<<<dim3(1024), blk, 0, stream>>>(lat, wnrc);

  // --- K (fused RoPE), V up-projections ---
  transpose_cvt<<<dim3(64, 16), blk, 0, stream>>>(wku, wkT, 512, 2048, probe);
  gemm_rope<<<dim3(16, 32), blk, 0, stream>>>(lat, wkT, kb, 4096, 2048, 512,
                                              fcosc, fsinc, 1.0f);
  transpose_cvt<<<dim3(64, 16), blk, 0, stream>>>(wvu, wvT, 512, 2048, probe);
  gemm_bt<<<dim3(16, 32), blk, 0, stream>>>(lat, wvT, vb, 4096, 2048, 512);

  // --- V -> (B,H,128,S); xc dead by now. w_out^T into dead wqT slot ---
  transpose_bf16<<<dim3(64, 64, 2), blk, 0, stream>>>(vb, vtb, 2048, 2048);
  transpose_cvt<<<dim3(64, 64), blk, 0, stream>>>(wo, woT, 2048, 2048, probe);

  // --- causal flash attention (ab aliases dead vb; x=bh, y=qb reversed) ---
  attn_kernel<<<dim3(32, 32), blk, 0, stream>>>(qb, kb, vtb, ab);

  // --- output projection into bf16 scratch (qb dead), then dtype-cast to d_out ---
  gemm_bt<<<dim3(16, 32), blk, 0, stream>>>(ab, woT, ob2, 4096, 2048, 2048);
  out_cvt<<<dim3(4096), blk, 0, stream>>>(ob2, d_out, 8388608, probe);
}